// Round 17
// baseline (151.156 us; speedup 1.0000x reference)
//
#include <hip/hip_runtime.h>

#define EPSF 1e-8f
#define PROB_PENALTYF 1e-4f
#define REV_SCALEF 0.1f
#define INFBITS 0x7F800000u

// verts grid (rev sources: 8000 ~N(0,1) pts): 32^3, h=0.35, span +-5.6
#define NV 32
#define HV 0.35f
#define LOV (-5.6f)
// barycenter grid (fwd sources: 16000 bc, sigma~0.577): 32^3, h=0.21875, +-3.5
#define NB 32
#define HB 0.21875f
#define LOB (-3.5f)

#define CPR 32768               // cells per region (32^3)
// regions: 0=V-src, 1=B-src, 2=V-query(rev), 3=B-query(fwd)
#define NCALL (4*CPR)

#define QBLK 64

__device__ __forceinline__ float min3f(float a, float b, float c) {
    return fminf(fminf(a, b), c);
}
__device__ __forceinline__ int cellc(float x, float lo, float invh, int n) {
    int c = (int)floorf((x - lo) * invh);
    return min(max(c, 0), n - 1);
}
__device__ __forceinline__ int vcell(float x, float y, float z) {
    return (cellc(z, LOV, 1.0f/HV, NV)*NV + cellc(y, LOV, 1.0f/HV, NV))*NV
         + cellc(x, LOV, 1.0f/HV, NV);
}
__device__ __forceinline__ int bcell(float x, float y, float z) {
    return (cellc(z, LOB, 1.0f/HB, NB)*NB + cellc(y, LOB, 1.0f/HB, NB))*NB
         + cellc(x, LOB, 1.0f/HB, NB);
}

// ---------------- kernel 0: zero counts + acc ----------------
__global__ void zero_kernel(unsigned* __restrict__ counts, float* __restrict__ acc) {
    int i = blockIdx.x * blockDim.x + threadIdx.x;
    if (i < NCALL) counts[i] = 0u;
    if (i < 8)     acc[i] = 0.0f;
}

// ---------------- kernel 1: count sources AND queries (+ materialize points) ----------------
__global__ void count_kernel(const float* __restrict__ overts,
                             const int* __restrict__ ofaces,
                             const float* __restrict__ sverts,
                             const int* __restrict__ sfaces,
                             const float* __restrict__ u1,
                             const float* __restrict__ u2,
                             const float* __restrict__ fp,
                             float4* __restrict__ obc4,
                             float4* __restrict__ revQ4,
                             float4* __restrict__ fwdQ4,
                             unsigned* __restrict__ counts,
                             int n_orig, int f_orig, int fs, int S, int npts) {
    int i = blockIdx.x * blockDim.x + threadIdx.x;
    const float third = 1.0f / 3.0f;
    if (i < n_orig) {
        float x = overts[3*i], y = overts[3*i+1], z = overts[3*i+2];
        atomicAdd(&counts[vcell(x, y, z)], 1u);
    }
    if (i < f_orig) {
        int a = ofaces[3*i], b = ofaces[3*i+1], c = ofaces[3*i+2];
        float x = (overts[3*a] + overts[3*b] + overts[3*c]) * third;
        float y = (overts[3*a+1] + overts[3*b+1] + overts[3*c+1]) * third;
        float z = (overts[3*a+2] + overts[3*b+2] + overts[3*c+2]) * third;
        obc4[i] = make_float4(x, y, z, 0.f);
        atomicAdd(&counts[CPR + bcell(x, y, z)], 1u);
    }
    if (i < npts) {
        int f = i / S;
        float rr = sqrtf(u1[i]);
        float uu = u2[i];
        float wa = 1.0f - rr, wb = rr * (1.0f - uu), wc = rr * uu;
        int a = sfaces[3*f], b = sfaces[3*f+1], c = sfaces[3*f+2];
        float x = wa * sverts[3*a] + wb * sverts[3*b] + wc * sverts[3*c];
        float y = wa * sverts[3*a+1] + wb * sverts[3*b+1] + wc * sverts[3*c+1];
        float z = wa * sverts[3*a+2] + wb * sverts[3*b+2] + wc * sverts[3*c+2];
        revQ4[i] = make_float4(x, y, z, fp[f]);
        atomicAdd(&counts[2*CPR + vcell(x, y, z)], 1u);
    }
    if (i < fs) {
        int a = sfaces[3*i], b = sfaces[3*i+1], c = sfaces[3*i+2];
        float x = (sverts[3*a] + sverts[3*b] + sverts[3*c]) * third;
        float y = (sverts[3*a+1] + sverts[3*b+1] + sverts[3*c+1]) * third;
        float z = (sverts[3*a+2] + sverts[3*b+2] + sverts[3*c+2]) * third;
        fwdQ4[i] = make_float4(x, y, z, fp[i]);
        atomicAdd(&counts[3*CPR + bcell(x, y, z)], 1u);
    }
}

// ---------------- kernel 2: scan — 128 blocks x 1024 cells, atomic region base ----------------
// Regions 0,1 share gcur[0] (one sortedS array); region 2 -> gcur[1] (sortedQR);
// region 3 -> gcur[2] (sortedQF). Base allocation order nondeterministic, but
// min/NN results are storage-order invariant. Rows of 32 cells never straddle a
// 1024-cell block => per-row start ranges are contiguous (query kernel relies).
__global__ void __launch_bounds__(1024)
scan_kernel(const unsigned* __restrict__ counts,
            unsigned* __restrict__ starts,
            unsigned* __restrict__ cursor,
            unsigned* __restrict__ gcur) {
    __shared__ unsigned sh[1024];
    __shared__ unsigned sbase;
    int t = (int)threadIdx.x;
    int idx = blockIdx.x * 1024 + t;
    int region = idx >> 15;
    int gi = (region < 2) ? 0 : (region - 1);
    unsigned c = counts[idx];
    sh[t] = c;
    __syncthreads();
    for (int off = 1; off < 1024; off <<= 1) {
        unsigned v = sh[t];
        unsigned add = (t >= off) ? sh[t - off] : 0u;
        __syncthreads();
        sh[t] = v + add;
        __syncthreads();
    }
    unsigned incl = sh[t];
    if (t == 1023) sbase = atomicAdd(&gcur[gi], incl);
    __syncthreads();
    unsigned st = sbase + incl - c;
    starts[idx] = st;
    cursor[idx] = st;
}

// ---------------- kernel 3: scatter sources + queries into sorted arrays ----------------
__global__ void scatter_kernel(const float* __restrict__ overts,
                               const float4* __restrict__ obc4,
                               const float4* __restrict__ revQ4,
                               const float4* __restrict__ fwdQ4,
                               unsigned* __restrict__ cursor,
                               float4* __restrict__ sortedS,
                               float4* __restrict__ sortedQR,
                               float4* __restrict__ sortedQF,
                               int n_orig, int f_orig, int npts, int fs) {
    int i = blockIdx.x * blockDim.x + threadIdx.x;
    if (i < n_orig) {
        float x = overts[3*i], y = overts[3*i+1], z = overts[3*i+2];
        unsigned pos = atomicAdd(&cursor[vcell(x, y, z)], 1u);
        sortedS[pos] = make_float4(x, y, z, 0.f);
    }
    if (i < f_orig) {
        float4 v = obc4[i];
        unsigned pos = atomicAdd(&cursor[CPR + bcell(v.x, v.y, v.z)], 1u);
        sortedS[pos] = v;
    }
    if (i < npts) {
        float4 q = revQ4[i];
        unsigned pos = atomicAdd(&cursor[2*CPR + vcell(q.x, q.y, q.z)], 1u);
        sortedQR[pos] = q;
    }
    if (i < fs) {
        float4 q = fwdQ4[i];
        unsigned pos = atomicAdd(&cursor[3*CPR + bcell(q.x, q.y, q.z)], 1u);
        sortedQF[pos] = q;
    }
}

// ---------------- kernel 4: grid 1-NN over CELL-SORTED queries + reduction ----------------
// One thread per sorted query: adjacent threads share a cell => identical
// candidate rows => L1-broadcast loads, lockstep trip counts. Cube phase:
// 9 contiguous row-ranges; 4-wide unrolled scan. Shell phase (rare, proven
// exact R13/R14): stop when best <= (r*h)^2.
__global__ void __launch_bounds__(QBLK)
query_kernel(const float4* __restrict__ sortedS,
             const unsigned* __restrict__ starts,
             const unsigned* __restrict__ counts,
             const float4* __restrict__ sortedQR,
             const float4* __restrict__ sortedQF,
             float* __restrict__ acc, float* __restrict__ out,
             int npts, int nq, int nblocks) {
    __shared__ float s1[QBLK], s2[QBLK], s3[QBLK];
    int t = blockIdx.x * blockDim.x + threadIdx.x;
    float fsum = 0.f, rsum = 0.f, rmx = 0.f;
    if (t < nq) {
        bool isRev = (t < npts);
        float4 q = isRev ? sortedQR[t] : sortedQF[t - npts];
        float qx = q.x, qy = q.y, qz = q.z, w = q.w;
        float lo = isRev ? LOV : LOB;
        float h  = isRev ? HV  : HB;
        int   n  = isRev ? NV  : NB;
        int   goff = isRev ? 0 : CPR;
        float invh = 1.0f / h;
        int cx = cellc(qx, lo, invh, n);
        int cy = cellc(qy, lo, invh, n);
        int cz = cellc(qz, lo, invh, n);
        float best = __uint_as_float(INFBITS);

        // ---- cube r<=1: 9 contiguous row-ranges ----
        unsigned rs[9], re[9];
        int x0 = max(cx-1, 0), x1 = min(cx+1, n-1);
        #pragma unroll
        for (int dz = -1; dz <= 1; ++dz) {
            int z = min(max(cz + dz, 0), n-1);
            #pragma unroll
            for (int dy = -1; dy <= 1; ++dy) {
                int y = min(max(cy + dy, 0), n-1);
                int rowc = goff + (z*n + y)*n;
                int k = (dz+1)*3 + (dy+1);
                rs[k] = starts[rowc + x0];
                re[k] = starts[rowc + x1] + counts[rowc + x1];
            }
        }
        #pragma unroll
        for (int k = 0; k < 9; ++k) {
            unsigned i = rs[k], e = re[k];
            for (; i + 4 <= e; i += 4) {
                float4 v0 = sortedS[i];
                float4 v1 = sortedS[i+1];
                float4 v2 = sortedS[i+2];
                float4 v3 = sortedS[i+3];
                float dx0 = qx-v0.x, dy0 = qy-v0.y, dz0 = qz-v0.z;
                float dx1 = qx-v1.x, dy1 = qy-v1.y, dz1 = qz-v1.z;
                float dx2 = qx-v2.x, dy2 = qy-v2.y, dz2 = qz-v2.z;
                float dx3 = qx-v3.x, dy3 = qy-v3.y, dz3 = qz-v3.z;
                float d0 = fmaf(dx0,dx0, fmaf(dy0,dy0, dz0*dz0));
                float d1 = fmaf(dx1,dx1, fmaf(dy1,dy1, dz1*dz1));
                float d2 = fmaf(dx2,dx2, fmaf(dy2,dy2, dz2*dz2));
                float d3 = fmaf(dx3,dx3, fmaf(dy3,dy3, dz3*dz3));
                best = min3f(best, d0, d1);
                best = min3f(best, d2, d3);
            }
            for (; i < e; ++i) {
                float4 v = sortedS[i];
                float dx = qx-v.x, dy = qy-v.y, dz = qz-v.z;
                best = fminf(best, fmaf(dx,dx, fmaf(dy,dy, dz*dz)));
            }
        }

        // ---- expanding shells (rare; proven exact) ----
        int rmaxq = max(max(cx, n-1-cx), max(max(cy, n-1-cy), max(cz, n-1-cz)));
        int r = 1;
        while (best > ((float)r * h) * ((float)r * h) && r < rmaxq) {
            ++r;
            for (int dz = -r; dz <= r; ++dz) {
                int z = cz + dz;
                if (z < 0 || z >= n) continue;
                bool zf = (dz == -r) || (dz == r);
                for (int dy = -r; dy <= r; ++dy) {
                    int y = cy + dy;
                    if (y < 0 || y >= n) continue;
                    bool yf = (dy == -r) || (dy == r);
                    int step = (zf || yf) ? 1 : 2 * r;
                    for (int dx = -r; dx <= r; dx += step) {
                        int x = cx + dx;
                        if (x < 0 || x >= n) continue;
                        int cid = goff + (z*n + y)*n + x;
                        unsigned sb = starts[cid];
                        unsigned e = sb + counts[cid];
                        for (unsigned i = sb; i < e; ++i) {
                            float4 v = sortedS[i];
                            float ddx = qx-v.x, ddy = qy-v.y, ddz = qz-v.z;
                            best = fminf(best, fmaf(ddx,ddx, fmaf(ddy,ddy, ddz*ddz)));
                        }
                    }
                }
            }
        }

        if (isRev) {
            rsum = w * best;
            rmx = best;
        } else {
            fsum = w * best + PROB_PENALTYF * (1.0f - w);
        }
    }

    // ---- block reduction + ticketed finalize ----
    s1[threadIdx.x] = fsum;
    s2[threadIdx.x] = rsum;
    s3[threadIdx.x] = rmx;
    __syncthreads();
    for (int off = QBLK / 2; off > 0; off >>= 1) {
        if ((int)threadIdx.x < off) {
            s1[threadIdx.x] += s1[threadIdx.x + off];
            s2[threadIdx.x] += s2[threadIdx.x + off];
            s3[threadIdx.x] = fmaxf(s3[threadIdx.x], s3[threadIdx.x + off]);
        }
        __syncthreads();
    }
    if (threadIdx.x == 0) {
        atomicAdd(&acc[0], s1[0]);
        atomicAdd(&acc[1], s2[0]);
        atomicMax((unsigned*)&acc[2], __float_as_uint(s3[0]));
        __threadfence();
        unsigned ticket = atomicAdd((unsigned*)&acc[3], 1u);
        if (ticket == (unsigned)(nblocks - 1)) {
            __threadfence();
            float a0 = atomicAdd(&acc[0], 0.0f);
            float a1 = atomicAdd(&acc[1], 0.0f);
            unsigned mb = atomicOr((unsigned*)&acc[2], 0u);
            out[0] = a0 + a1 * (REV_SCALEF / (__uint_as_float(mb) + EPSF));
        }
    }
}

extern "C" void kernel_launch(void* const* d_in, const int* in_sizes, int n_in,
                              void* d_out, int out_size, void* d_ws, size_t ws_size,
                              hipStream_t stream) {
    const float* overts = (const float*)d_in[0];
    const int*   ofaces = (const int*)d_in[1];
    const float* sverts = (const float*)d_in[2];
    const int*   sfaces = (const int*)d_in[3];
    const float* fp     = (const float*)d_in[4];
    const float* u1     = (const float*)d_in[5];
    const float* u2     = (const float*)d_in[6];
    float* out = (float*)d_out;

    const int N_ORIG = in_sizes[0] / 3;
    const int F_ORIG = in_sizes[1] / 3;
    const int F_SIMP = in_sizes[3] / 3;
    const int S      = in_sizes[5] / F_SIMP;
    const int NPTS   = F_SIMP * S;
    const int NQ     = NPTS + F_SIMP;

    // workspace layout (float4 arrays first)
    float4* sortedS  = (float4*)d_ws;                   // N_ORIG + F_ORIG
    float4* sortedQR = sortedS + (N_ORIG + F_ORIG);     // NPTS
    float4* sortedQF = sortedQR + NPTS;                 // F_SIMP
    float4* obc4     = sortedQF + F_SIMP;               // F_ORIG
    float4* revQ4    = obc4 + F_ORIG;                   // NPTS
    float4* fwdQ4    = revQ4 + NPTS;                    // F_SIMP
    unsigned* counts = (unsigned*)(fwdQ4 + F_SIMP);     // NCALL
    unsigned* starts = counts + NCALL;                  // NCALL
    unsigned* cursor = starts + NCALL;                  // NCALL
    float* acc = (float*)(cursor + NCALL);              // 8 floats
    unsigned* gcur = (unsigned*)acc + 4;                // acc[4..6] = region bases

    hipLaunchKernelGGL(zero_kernel, dim3(NCALL / 256), dim3(256), 0, stream, counts, acc);

    int cntN = max(max(N_ORIG, F_ORIG), NPTS);
    hipLaunchKernelGGL(count_kernel, dim3((cntN + 255) / 256), dim3(256), 0, stream,
                       overts, ofaces, sverts, sfaces, u1, u2, fp,
                       obc4, revQ4, fwdQ4, counts,
                       N_ORIG, F_ORIG, F_SIMP, S, NPTS);

    hipLaunchKernelGGL(scan_kernel, dim3(NCALL / 1024), dim3(1024), 0, stream,
                       counts, starts, cursor, gcur);

    hipLaunchKernelGGL(scatter_kernel, dim3((cntN + 255) / 256), dim3(256), 0, stream,
                       overts, obc4, revQ4, fwdQ4, cursor,
                       sortedS, sortedQR, sortedQF,
                       N_ORIG, F_ORIG, NPTS, F_SIMP);

    const int qblocks = (NQ + QBLK - 1) / QBLK;
    hipLaunchKernelGGL(query_kernel, dim3(qblocks), dim3(QBLK), 0, stream,
                       sortedS, starts, counts, sortedQR, sortedQF,
                       acc, out, NPTS, NQ, qblocks);
}

// Round 18
// 119.599 us; speedup vs baseline: 1.2639x; 1.2639x over previous
//
#include <hip/hip_runtime.h>

#define EPSF 1e-8f
#define PROB_PENALTYF 1e-4f
#define REV_SCALEF 0.1f
#define INFBITS 0x7F800000u

// verts grid (rev sources: 8000 ~N(0,1) pts): 32^3, h=0.35, span +-5.6
#define NV 32
#define HV 0.35f
#define LOV (-5.6f)
// barycenter grid (fwd sources: 16000 bc, sigma~0.577): 32^3, h=0.15, +-2.4
#define NB 32
#define HB 0.15f
#define LOB (-2.4f)

#define CPR 32768               // cells per region (32^3)
// regions: 0=V-src, 1=B-src, 2=V-query(rev), 3=B-query(fwd); separate bases
#define NCALL (4*CPR)

#define QBLK 256
#define BFBLK 256
#define BFBLOCKS 64

__device__ __forceinline__ float min3f(float a, float b, float c) {
    return fminf(fminf(a, b), c);
}
__device__ __forceinline__ int cellc(float x, float lo, float invh, int n) {
    int c = (int)floorf((x - lo) * invh);
    return min(max(c, 0), n - 1);
}
__device__ __forceinline__ int vcell(float x, float y, float z) {
    return (cellc(z, LOV, 1.0f/HV, NV)*NV + cellc(y, LOV, 1.0f/HV, NV))*NV
         + cellc(x, LOV, 1.0f/HV, NV);
}
__device__ __forceinline__ int bcell(float x, float y, float z) {
    return (cellc(z, LOB, 1.0f/HB, NB)*NB + cellc(y, LOB, 1.0f/HB, NB))*NB
         + cellc(x, LOB, 1.0f/HB, NB);
}

// acc layout (unsigned view): [0]=fsum(f32) [1]=rsum(f32) [2]=rmax bits
// [3]=unused [4..7]=region bases (gcur) [8]=bf count [9]=bf ticket
__global__ void zero_kernel(unsigned* __restrict__ counts,
                            unsigned* __restrict__ accu, int n_orig) {
    int i = blockIdx.x * blockDim.x + threadIdx.x;
    if (i < NCALL) counts[i] = 0u;
    if (i < 12)    accu[i] = (i == 5) ? (unsigned)n_orig : 0u;  // region1 base = N_ORIG
}

// ---------------- kernel 1: count sources AND queries (+ materialize points) ----------------
__global__ void count_kernel(const float* __restrict__ overts,
                             const int* __restrict__ ofaces,
                             const float* __restrict__ sverts,
                             const int* __restrict__ sfaces,
                             const float* __restrict__ u1,
                             const float* __restrict__ u2,
                             const float* __restrict__ fp,
                             float4* __restrict__ obc4,
                             float4* __restrict__ revQ4,
                             float4* __restrict__ fwdQ4,
                             unsigned* __restrict__ counts,
                             int n_orig, int f_orig, int fs, int S, int npts) {
    int i = blockIdx.x * blockDim.x + threadIdx.x;
    const float third = 1.0f / 3.0f;
    if (i < n_orig) {
        float x = overts[3*i], y = overts[3*i+1], z = overts[3*i+2];
        atomicAdd(&counts[vcell(x, y, z)], 1u);
    }
    if (i < f_orig) {
        int a = ofaces[3*i], b = ofaces[3*i+1], c = ofaces[3*i+2];
        float x = (overts[3*a] + overts[3*b] + overts[3*c]) * third;
        float y = (overts[3*a+1] + overts[3*b+1] + overts[3*c+1]) * third;
        float z = (overts[3*a+2] + overts[3*b+2] + overts[3*c+2]) * third;
        obc4[i] = make_float4(x, y, z, 0.f);
        atomicAdd(&counts[CPR + bcell(x, y, z)], 1u);
    }
    if (i < npts) {
        int f = i / S;
        float rr = sqrtf(u1[i]);
        float uu = u2[i];
        float wa = 1.0f - rr, wb = rr * (1.0f - uu), wc = rr * uu;
        int a = sfaces[3*f], b = sfaces[3*f+1], c = sfaces[3*f+2];
        float x = wa * sverts[3*a] + wb * sverts[3*b] + wc * sverts[3*c];
        float y = wa * sverts[3*a+1] + wb * sverts[3*b+1] + wc * sverts[3*c+1];
        float z = wa * sverts[3*a+2] + wb * sverts[3*b+2] + wc * sverts[3*c+2];
        revQ4[i] = make_float4(x, y, z, fp[f]);
        atomicAdd(&counts[2*CPR + vcell(x, y, z)], 1u);
    }
    if (i < fs) {
        int a = sfaces[3*i], b = sfaces[3*i+1], c = sfaces[3*i+2];
        float x = (sverts[3*a] + sverts[3*b] + sverts[3*c]) * third;
        float y = (sverts[3*a+1] + sverts[3*b+1] + sverts[3*c+1]) * third;
        float z = (sverts[3*a+2] + sverts[3*b+2] + sverts[3*c+2]) * third;
        fwdQ4[i] = make_float4(x, y, z, fp[i]);
        atomicAdd(&counts[3*CPR + bcell(x, y, z)], 1u);
    }
}

// ---------------- kernel 2: scan — 128 blocks x 1024 cells, per-region atomic base ----------------
// Region r uses gcur[r] (region0 base 0 => V sources occupy sortedS[0,N_ORIG);
// region1 base N_ORIG => B sources occupy [N_ORIG, N_ORIG+F_ORIG)). Base order
// nondeterministic, but min/NN results are storage-order invariant. Rows of 32
// cells never straddle a 1024-cell block => per-row start ranges contiguous.
__global__ void __launch_bounds__(1024)
scan_kernel(const unsigned* __restrict__ counts,
            unsigned* __restrict__ starts,
            unsigned* __restrict__ cursor,
            unsigned* __restrict__ gcur) {
    __shared__ unsigned sh[1024];
    __shared__ unsigned sbase;
    int t = (int)threadIdx.x;
    int idx = blockIdx.x * 1024 + t;
    int region = idx >> 15;
    unsigned c = counts[idx];
    sh[t] = c;
    __syncthreads();
    for (int off = 1; off < 1024; off <<= 1) {
        unsigned v = sh[t];
        unsigned add = (t >= off) ? sh[t - off] : 0u;
        __syncthreads();
        sh[t] = v + add;
        __syncthreads();
    }
    unsigned incl = sh[t];
    if (t == 1023) sbase = atomicAdd(&gcur[region], incl);
    __syncthreads();
    unsigned st = sbase + incl - c;
    starts[idx] = st;
    cursor[idx] = st;
}

// ---------------- kernel 3: scatter sources + queries into sorted arrays ----------------
__global__ void scatter_kernel(const float* __restrict__ overts,
                               const float4* __restrict__ obc4,
                               const float4* __restrict__ revQ4,
                               const float4* __restrict__ fwdQ4,
                               unsigned* __restrict__ cursor,
                               float4* __restrict__ sortedS,
                               float4* __restrict__ sortedQR,
                               float4* __restrict__ sortedQF,
                               int n_orig, int f_orig, int npts, int fs) {
    int i = blockIdx.x * blockDim.x + threadIdx.x;
    if (i < n_orig) {
        float x = overts[3*i], y = overts[3*i+1], z = overts[3*i+2];
        unsigned pos = atomicAdd(&cursor[vcell(x, y, z)], 1u);
        sortedS[pos] = make_float4(x, y, z, 0.f);
    }
    if (i < f_orig) {
        float4 v = obc4[i];
        unsigned pos = atomicAdd(&cursor[CPR + bcell(v.x, v.y, v.z)], 1u);
        sortedS[pos] = v;
    }
    if (i < npts) {
        float4 q = revQ4[i];
        unsigned pos = atomicAdd(&cursor[2*CPR + vcell(q.x, q.y, q.z)], 1u);
        sortedQR[pos] = q;
    }
    if (i < fs) {
        float4 q = fwdQ4[i];
        unsigned pos = atomicAdd(&cursor[3*CPR + bcell(q.x, q.y, q.z)], 1u);
        sortedQF[pos] = q;
    }
}

// ---------------- kernel 4: cube-only grid 1-NN over sorted queries ----------------
// Exactness test: after scanning the 27-cell cube, best <= h*h guarantees no
// closer point exists outside (any cell at Chebyshev index-dist >= 2 is >= h
// away along that axis, valid under clamping both ways). Queries failing the
// test are appended to bfList and resolved exactly by bf_kernel.
__global__ void __launch_bounds__(QBLK)
query_kernel(const float4* __restrict__ sortedS,
             const unsigned* __restrict__ starts,
             const unsigned* __restrict__ counts,
             const float4* __restrict__ sortedQR,
             const float4* __restrict__ sortedQF,
             unsigned* __restrict__ bfList,
             float* __restrict__ acc,
             int npts, int nq) {
    __shared__ float s1[QBLK], s2[QBLK], s3[QBLK];
    int t = blockIdx.x * blockDim.x + threadIdx.x;
    float fsum = 0.f, rsum = 0.f, rmx = 0.f;
    if (t < nq) {
        bool isRev = (t < npts);
        float4 q = isRev ? sortedQR[t] : sortedQF[t - npts];
        float qx = q.x, qy = q.y, qz = q.z, w = q.w;
        float lo = isRev ? LOV : LOB;
        float h  = isRev ? HV  : HB;
        int   n  = isRev ? NV  : NB;
        int   goff = isRev ? 0 : CPR;
        float invh = 1.0f / h;
        int cx = cellc(qx, lo, invh, n);
        int cy = cellc(qy, lo, invh, n);
        int cz = cellc(qz, lo, invh, n);
        float best = __uint_as_float(INFBITS);

        // ---- 27-cell cube as 9 contiguous row-ranges ----
        unsigned rs[9], re[9];
        int x0 = max(cx-1, 0), x1 = min(cx+1, n-1);
        #pragma unroll
        for (int dz = -1; dz <= 1; ++dz) {
            int z = min(max(cz + dz, 0), n-1);
            #pragma unroll
            for (int dy = -1; dy <= 1; ++dy) {
                int y = min(max(cy + dy, 0), n-1);
                int rowc = goff + (z*n + y)*n;
                int k = (dz+1)*3 + (dy+1);
                rs[k] = starts[rowc + x0];
                re[k] = starts[rowc + x1] + counts[rowc + x1];
            }
        }
        #pragma unroll
        for (int k = 0; k < 9; ++k) {
            unsigned i = rs[k], e = re[k];
            for (; i + 4 <= e; i += 4) {
                float4 v0 = sortedS[i];
                float4 v1 = sortedS[i+1];
                float4 v2 = sortedS[i+2];
                float4 v3 = sortedS[i+3];
                float dx0 = qx-v0.x, dy0 = qy-v0.y, dz0 = qz-v0.z;
                float dx1 = qx-v1.x, dy1 = qy-v1.y, dz1 = qz-v1.z;
                float dx2 = qx-v2.x, dy2 = qy-v2.y, dz2 = qz-v2.z;
                float dx3 = qx-v3.x, dy3 = qy-v3.y, dz3 = qz-v3.z;
                float d0 = fmaf(dx0,dx0, fmaf(dy0,dy0, dz0*dz0));
                float d1 = fmaf(dx1,dx1, fmaf(dy1,dy1, dz1*dz1));
                float d2 = fmaf(dx2,dx2, fmaf(dy2,dy2, dz2*dz2));
                float d3 = fmaf(dx3,dx3, fmaf(dy3,dy3, dz3*dz3));
                best = min3f(best, d0, d1);
                best = min3f(best, d2, d3);
            }
            for (; i < e; ++i) {
                float4 v = sortedS[i];
                float dx = qx-v.x, dy = qy-v.y, dz = qz-v.z;
                best = fminf(best, fmaf(dx,dx, fmaf(dy,dy, dz*dz)));
            }
        }

        if (best <= h * h) {
            if (isRev) { rsum = w * best; rmx = best; }
            else       { fsum = w * best + PROB_PENALTYF * (1.0f - w); }
        } else {
            unsigned li = atomicAdd((unsigned*)acc + 8, 1u);
            bfList[li] = (unsigned)t;
        }
    }

    // ---- block reduction (no ticket; bf_kernel finalizes) ----
    s1[threadIdx.x] = fsum;
    s2[threadIdx.x] = rsum;
    s3[threadIdx.x] = rmx;
    __syncthreads();
    for (int off = QBLK / 2; off > 0; off >>= 1) {
        if ((int)threadIdx.x < off) {
            s1[threadIdx.x] += s1[threadIdx.x + off];
            s2[threadIdx.x] += s2[threadIdx.x + off];
            s3[threadIdx.x] = fmaxf(s3[threadIdx.x], s3[threadIdx.x + off]);
        }
        __syncthreads();
    }
    if (threadIdx.x == 0) {
        atomicAdd(&acc[0], s1[0]);
        atomicAdd(&acc[1], s2[0]);
        atomicMax((unsigned*)&acc[2], __float_as_uint(s3[0]));
    }
}

// ---------------- kernel 5: brute-force tail queries + final scalar ----------------
// One wave per list entry (round-robin): 64-lane coalesced stream over the full
// source region (exact by construction). Fixed grid => fixed ticket count; the
// last block writes out (query_kernel finished at kernel boundary).
__global__ void __launch_bounds__(BFBLK)
bf_kernel(const float4* __restrict__ sortedS,
          const float4* __restrict__ sortedQR,
          const float4* __restrict__ sortedQF,
          const unsigned* __restrict__ bfList,
          float* __restrict__ acc, float* __restrict__ out,
          int n_orig, int f_orig, int npts, int nblocks) {
    unsigned nbf = ((unsigned*)acc)[8];
    int wib = (int)threadIdx.x >> 6;
    int lane = (int)threadIdx.x & 63;
    int wid = blockIdx.x * (BFBLK / 64) + wib;
    int nwaves = nblocks * (BFBLK / 64);
    float fsum = 0.f, rsum = 0.f, rmx = 0.f;

    for (unsigned e = (unsigned)wid; e < nbf; e += (unsigned)nwaves) {
        unsigned t = bfList[e];
        bool isRev = (t < (unsigned)npts);
        float4 q = isRev ? sortedQR[t] : sortedQF[t - npts];
        int base = isRev ? 0 : n_orig;
        int cnt  = isRev ? n_orig : f_orig;
        float best = __uint_as_float(INFBITS);
        for (int i = lane; i < cnt; i += 64) {
            float4 v = sortedS[base + i];
            float dx = q.x-v.x, dy = q.y-v.y, dz = q.z-v.z;
            best = fminf(best, fmaf(dx,dx, fmaf(dy,dy, dz*dz)));
        }
        #pragma unroll
        for (int off = 1; off < 64; off <<= 1)
            best = fminf(best, __shfl_xor(best, off));
        if (lane == 0) {
            if (isRev) { rsum += q.w * best; rmx = fmaxf(rmx, best); }
            else       { fsum += q.w * best + PROB_PENALTYF * (1.0f - q.w); }
        }
    }
    if (lane == 0) {
        atomicAdd(&acc[0], fsum);
        atomicAdd(&acc[1], rsum);
        atomicMax((unsigned*)&acc[2], __float_as_uint(rmx));
        __threadfence();
    }
    __syncthreads();
    if (threadIdx.x == 0) {
        unsigned ticket = atomicAdd((unsigned*)acc + 9, 1u);
        if (ticket == (unsigned)(nblocks - 1)) {
            __threadfence();
            float a0 = atomicAdd(&acc[0], 0.0f);
            float a1 = atomicAdd(&acc[1], 0.0f);
            unsigned mb = atomicOr((unsigned*)&acc[2], 0u);
            out[0] = a0 + a1 * (REV_SCALEF / (__uint_as_float(mb) + EPSF));
        }
    }
}

extern "C" void kernel_launch(void* const* d_in, const int* in_sizes, int n_in,
                              void* d_out, int out_size, void* d_ws, size_t ws_size,
                              hipStream_t stream) {
    const float* overts = (const float*)d_in[0];
    const int*   ofaces = (const int*)d_in[1];
    const float* sverts = (const float*)d_in[2];
    const int*   sfaces = (const int*)d_in[3];
    const float* fp     = (const float*)d_in[4];
    const float* u1     = (const float*)d_in[5];
    const float* u2     = (const float*)d_in[6];
    float* out = (float*)d_out;

    const int N_ORIG = in_sizes[0] / 3;
    const int F_ORIG = in_sizes[1] / 3;
    const int F_SIMP = in_sizes[3] / 3;
    const int S      = in_sizes[5] / F_SIMP;
    const int NPTS   = F_SIMP * S;
    const int NQ     = NPTS + F_SIMP;

    // workspace layout (float4 arrays first)
    float4* sortedS  = (float4*)d_ws;                   // N_ORIG + F_ORIG
    float4* sortedQR = sortedS + (N_ORIG + F_ORIG);     // NPTS
    float4* sortedQF = sortedQR + NPTS;                 // F_SIMP
    float4* obc4     = sortedQF + F_SIMP;               // F_ORIG
    float4* revQ4    = obc4 + F_ORIG;                   // NPTS
    float4* fwdQ4    = revQ4 + NPTS;                    // F_SIMP
    unsigned* counts = (unsigned*)(fwdQ4 + F_SIMP);     // NCALL
    unsigned* starts = counts + NCALL;                  // NCALL
    unsigned* cursor = starts + NCALL;                  // NCALL
    unsigned* bfList = cursor + NCALL;                  // NQ
    float* acc = (float*)(bfList + NQ);                 // 16 floats
    unsigned* gcur = (unsigned*)acc + 4;

    hipLaunchKernelGGL(zero_kernel, dim3(NCALL / 256), dim3(256), 0, stream,
                       counts, (unsigned*)acc, N_ORIG);

    int cntN = max(max(N_ORIG, F_ORIG), NPTS);
    hipLaunchKernelGGL(count_kernel, dim3((cntN + 255) / 256), dim3(256), 0, stream,
                       overts, ofaces, sverts, sfaces, u1, u2, fp,
                       obc4, revQ4, fwdQ4, counts,
                       N_ORIG, F_ORIG, F_SIMP, S, NPTS);

    hipLaunchKernelGGL(scan_kernel, dim3(NCALL / 1024), dim3(1024), 0, stream,
                       counts, starts, cursor, gcur);

    hipLaunchKernelGGL(scatter_kernel, dim3((cntN + 255) / 256), dim3(256), 0, stream,
                       overts, obc4, revQ4, fwdQ4, cursor,
                       sortedS, sortedQR, sortedQF,
                       N_ORIG, F_ORIG, NPTS, F_SIMP);

    const int qblocks = (NQ + QBLK - 1) / QBLK;
    hipLaunchKernelGGL(query_kernel, dim3(qblocks), dim3(QBLK), 0, stream,
                       sortedS, starts, counts, sortedQR, sortedQF,
                       bfList, acc, NPTS, NQ);

    hipLaunchKernelGGL(bf_kernel, dim3(BFBLOCKS), dim3(BFBLK), 0, stream,
                       sortedS, sortedQR, sortedQF, bfList,
                       acc, out, N_ORIG, F_ORIG, NPTS, BFBLOCKS);
}

// Round 19
// 43.887 us; speedup vs baseline: 3.4442x; 2.7252x over previous
//
#include <hip/hip_runtime.h>

#define EPSF 1e-8f
#define PROB_PENALTYF 1e-4f
#define REV_SCALEF 0.1f
#define INFBITS 0x7F800000u
#define ONEBF ((unsigned short)0x3F80)   // bf16 1.0
#define SENT_C 1.0e6f

#define PTW 4     // point-tiles per wave (reuse: each B-load feeds 4 MFMAs)
#define WPB 4     // waves per block (256 threads)
#define CS 32     // source tiles per chunk -> 10016 waves (~9.8/SIMD demanded)
#define FBLK 256

typedef __attribute__((ext_vector_type(8))) short short8;   // 8 bf16 (4 VGPRs)
typedef __attribute__((ext_vector_type(4))) float f32x4;

__device__ __forceinline__ float min3f(float a, float b, float c) {
    return fminf(fminf(a, b), c);   // -> v_min3_f32
}

// ---- bf16 helpers (RTN split: f = hi + lo to ~2^-17 relative) ----
__device__ __forceinline__ unsigned short bfh(float f) {
    unsigned u = __float_as_uint(f);
    return (unsigned short)((u + 0x7FFFu + ((u >> 16) & 1u)) >> 16);
}
__device__ __forceinline__ float bftof(unsigned short h) {
    return __uint_as_float(((unsigned)h) << 16);
}
__device__ __forceinline__ unsigned short bfl(float f, unsigned short h) {
    return bfh(f - bftof(h));
}
__device__ __forceinline__ unsigned pk(unsigned short lo, unsigned short hi) {
    return (unsigned)lo | ((unsigned)hi << 16);
}

// K-slot packing (A row side holds point P={tx,ty,tz,p2}, t=-2p; B col side
// holds source V={vx,vy,vz,v2}). Sum over k of A[k]*B[k] =
//   k0-2 : t_hi.xyz * v_hi.xyz ; k3-5 : t_lo.xyz * v_hi.xyz
//   k6-8 : t_hi.xyz * v_lo.xyz ; k9-10: 1.0 * v2_hi, v2_lo
//   k11-12: p2_hi,p2_lo * 1.0  ; k13-31: zero (lanes 32-63 hold zero A-frags)
// => D[row][col] = |p|^2 + |v|^2 - 2 p.v  at ~fp32 precision. (HW-verified R7+)
__device__ __forceinline__ uint4 makeAfrag(float x, float y, float z, float w, int g) {
    unsigned short hx = bfh(x), hy = bfh(y), hz = bfh(z);
    uint4 r;
    if (g == 0) {
        unsigned short lx = bfl(x, hx), ly = bfl(y, hy), lz = bfl(z, hz);
        r.x = pk(hx, hy); r.y = pk(hz, lx); r.z = pk(ly, lz); r.w = pk(hx, hy);
    } else {
        unsigned short hw = bfh(w), lw = bfl(w, hw);
        r.x = pk(hz, ONEBF); r.y = pk(ONEBF, hw); r.z = pk(lw, 0); r.w = 0u;
    }
    return r;
}
__device__ __forceinline__ uint4 makeBfrag(float x, float y, float z, float w, int g) {
    unsigned short hx = bfh(x), hy = bfh(y), hz = bfh(z);
    uint4 r;
    if (g == 0) {
        unsigned short lx = bfl(x, hx), ly = bfl(y, hy);
        r.x = pk(hx, hy); r.y = pk(hz, hx); r.z = pk(hy, hz); r.w = pk(lx, ly);
    } else {
        unsigned short lz = bfl(z, hz);
        unsigned short hw = bfh(w), lw = bfl(w, hw);
        r.x = pk(lz, hw); r.y = pk(lw, ONEBF); r.z = pk(ONEBF, 0); r.w = 0u;
    }
    return r;
}

// ---------------- kernel 0: prep (build all MFMA fragments + init) ----------------
__global__ void prep_kernel(const float* __restrict__ overts,
                            const int* __restrict__ ofaces,
                            const float* __restrict__ sverts,
                            const int* __restrict__ sfaces,
                            const float* __restrict__ u1,
                            const float* __restrict__ u2,
                            uint4* __restrict__ revA, uint4* __restrict__ fwdA,
                            uint4* __restrict__ revB, uint4* __restrict__ fwdB,
                            unsigned* __restrict__ rev_min,
                            unsigned* __restrict__ fwd_min,
                            float* __restrict__ acc,
                            int n_orig, int f_orig, int fs, int S, int npts,
                            int revPt, int fwdPt, int revSt, int fwdSt) {
    int tid = blockIdx.x * blockDim.x + threadIdx.x;
    const float third = 1.0f / 3.0f;
    int r0 = revPt * 32, r1 = r0 + fwdPt * 32, r2 = r1 + revSt * 32, r3 = r2 + fwdSt * 32;

    if (tid < r0) {
        int l = tid & 31, g = l >> 4;
        int k = (tid >> 5) * 16 + (l & 15);
        float x = 0.f, y = 0.f, z = 0.f;
        if (k < npts) {
            int f = k / S;
            float rr = sqrtf(u1[k]);
            float uu = u2[k];
            float wa = 1.0f - rr, wb = rr * (1.0f - uu), wc = rr * uu;
            int a = sfaces[3 * f], b = sfaces[3 * f + 1], c = sfaces[3 * f + 2];
            x = wa * sverts[3 * a] + wb * sverts[3 * b] + wc * sverts[3 * c];
            y = wa * sverts[3 * a + 1] + wb * sverts[3 * b + 1] + wc * sverts[3 * c + 1];
            z = wa * sverts[3 * a + 2] + wb * sverts[3 * b + 2] + wc * sverts[3 * c + 2];
        }
        float p2 = x * x + y * y + z * z;
        revA[tid] = makeAfrag(-2.f * x, -2.f * y, -2.f * z, p2, g);
    } else if (tid < r1) {
        int t2 = tid - r0;
        int l = t2 & 31, g = l >> 4;
        int k = (t2 >> 5) * 16 + (l & 15);
        float x = 0.f, y = 0.f, z = 0.f;
        if (k < fs) {
            int a = sfaces[3 * k], b = sfaces[3 * k + 1], c = sfaces[3 * k + 2];
            x = (sverts[3 * a] + sverts[3 * b] + sverts[3 * c]) * third;
            y = (sverts[3 * a + 1] + sverts[3 * b + 1] + sverts[3 * c + 1]) * third;
            z = (sverts[3 * a + 2] + sverts[3 * b + 2] + sverts[3 * c + 2]) * third;
        }
        float p2 = x * x + y * y + z * z;
        fwdA[t2] = makeAfrag(-2.f * x, -2.f * y, -2.f * z, p2, g);
    } else if (tid < r2) {
        int t2 = tid - r1;
        int l = t2 & 31, g = l >> 4;
        int s = (t2 >> 5) * 16 + (l & 15);
        float x = SENT_C, y = SENT_C, z = SENT_C;
        if (s < n_orig) { x = overts[3 * s]; y = overts[3 * s + 1]; z = overts[3 * s + 2]; }
        revB[t2] = makeBfrag(x, y, z, x * x + y * y + z * z, g);
    } else if (tid < r3) {
        int t2 = tid - r2;
        int l = t2 & 31, g = l >> 4;
        int s = (t2 >> 5) * 16 + (l & 15);
        float x = SENT_C, y = SENT_C, z = SENT_C;
        if (s < f_orig) {
            int a = ofaces[3 * s], b = ofaces[3 * s + 1], c = ofaces[3 * s + 2];
            x = (overts[3 * a] + overts[3 * b] + overts[3 * c]) * third;
            y = (overts[3 * a + 1] + overts[3 * b + 1] + overts[3 * c + 1]) * third;
            z = (overts[3 * a + 2] + overts[3 * b + 2] + overts[3 * c + 2]) * third;
        }
        fwdB[t2] = makeBfrag(x, y, z, x * x + y * y + z * z, g);
    } else {
        int t2 = tid - r3;
        if (t2 < npts) rev_min[t2] = INFBITS;
        if (t2 < fs)   fwd_min[t2] = INFBITS;
        if (t2 < 8)    acc[t2] = 0.0f;
    }
}

// ---------------- kernel 1: MFMA min-distance (PTW=4, CS=32, 6 waves/SIMD) ----------------
__global__ void __launch_bounds__(256, 6)
mfma_min_kernel(const uint4* __restrict__ revA, const uint4* __restrict__ fwdA,
                const uint4* __restrict__ revB, const uint4* __restrict__ fwdB,
                unsigned* __restrict__ rev_min, unsigned* __restrict__ fwd_min,
                int revGroups, int revWaves, int revPt, int revNpts, int revSt,
                int fwdGroups, int fwdPt, int fwdNpts, int fwdSt,
                int totalWaves) {
    int gw = blockIdx.x * WPB + ((int)threadIdx.x >> 6);
    if (gw >= totalWaves) return;
    int lane = (int)threadIdx.x & 63;

    const uint4 *A, *B;
    unsigned* omin;
    int group, chunk, nTile, npts, nst;
    if (gw < revWaves) {
        A = revA; B = revB; omin = rev_min; nTile = revPt; npts = revNpts; nst = revSt;
        group = gw % revGroups; chunk = gw / revGroups;
    } else {
        int g2 = gw - revWaves;
        A = fwdA; B = fwdB; omin = fwd_min; nTile = fwdPt; npts = fwdNpts; nst = fwdSt;
        group = g2 % fwdGroups; chunk = g2 / fwdGroups;
    }
    int s0 = chunk * CS;
    int ns = min(CS, nst - s0);

    const short8* A8 = reinterpret_cast<const short8*>(A);
    const short8* B8 = reinterpret_cast<const short8*>(B);

    // A-frags (lanes 0-31 data; lanes 32-63 zero => k16-31 dead)
    const short8 zero8 = {0, 0, 0, 0, 0, 0, 0, 0};
    short8 a[PTW];
    int pt0 = group * PTW;
    #pragma unroll
    for (int r = 0; r < PTW; ++r) {
        int ptile = min(pt0 + r, nTile - 1);
        short8 av = A8[(size_t)ptile * 32 + (lane & 31)];
        a[r] = (lane < 32) ? av : zero8;
    }

    float inf = __uint_as_float(INFBITS);
    f32x4 m[PTW];
    #pragma unroll
    for (int r = 0; r < PTW; ++r) m[r] = (f32x4){inf, inf, inf, inf};
    f32x4 cz = {0.f, 0.f, 0.f, 0.f};
    const short8* bp = B8 + (size_t)s0 * 32 + (lane & 31);

#define COMPUTE(BB)                                                              \
    do {                                                                         \
        _Pragma("unroll")                                                        \
        for (int r = 0; r < PTW; ++r) {                                          \
            f32x4 d = __builtin_amdgcn_mfma_f32_16x16x32_bf16(a[r], (BB), cz, 0, 0, 0); \
            m[r].x = fminf(m[r].x, d.x); m[r].y = fminf(m[r].y, d.y);            \
            m[r].z = fminf(m[r].z, d.z); m[r].w = fminf(m[r].w, d.w);            \
        }                                                                        \
    } while (0)

    // prefetch depth 2, unroll 2. May read up to 3 tiles past the chunk end:
    // valid workspace memory (next region / min arrays), values discarded.
    short8 b0 = bp[0];
    short8 b1 = bp[32];
    int s = 0;
    for (; s + 2 <= ns; s += 2) {
        short8 n0 = bp[(s + 2) * 32];
        short8 n1 = bp[(s + 3) * 32];
        COMPUTE(b0);
        COMPUTE(b1);
        b0 = n0; b1 = n1;
    }
    if (s < ns) COMPUTE(b0);
#undef COMPUTE

    // min over the 16 cols = min across the 16 lanes of each lane-group
    #pragma unroll
    for (int off = 1; off < 16; off <<= 1) {
        #pragma unroll
        for (int r = 0; r < PTW; ++r) {
            m[r].x = fminf(m[r].x, __shfl_xor(m[r].x, off));
            m[r].y = fminf(m[r].y, __shfl_xor(m[r].y, off));
            m[r].z = fminf(m[r].z, __shfl_xor(m[r].z, off));
            m[r].w = fminf(m[r].w, __shfl_xor(m[r].w, off));
        }
    }

    if ((lane & 15) == 0) {
        int rowbase = (lane >> 4) * 4;   // D row = (lane>>4)*4 + reg
        #pragma unroll
        for (int r = 0; r < PTW; ++r) {
            int pb = min(pt0 + r, nTile - 1) * 16 + rowbase;
            if (pb + 0 < npts) atomicMin(&omin[pb + 0], __float_as_uint(fmaxf(m[r].x, 0.f)));
            if (pb + 1 < npts) atomicMin(&omin[pb + 1], __float_as_uint(fmaxf(m[r].y, 0.f)));
            if (pb + 2 < npts) atomicMin(&omin[pb + 2], __float_as_uint(fmaxf(m[r].z, 0.f)));
            if (pb + 3 < npts) atomicMin(&omin[pb + 3], __float_as_uint(fmaxf(m[r].w, 0.f)));
        }
    }
}

// ---------------- kernel 2: reductions + final scalar (last-block writes out) ----------------
__global__ void finalize_kernel(const unsigned int* __restrict__ fwd_min,
                                const unsigned int* __restrict__ rev_min,
                                const float* __restrict__ fp,
                                float* acc, float* out,
                                int fs, int npts, int S, int nblocks) {
    __shared__ float s1[FBLK], s2[FBLK], s3[FBLK];
    int k = blockIdx.x * blockDim.x + threadIdx.x;
    float fsum = 0.f, rsum = 0.f, rmax = 0.f;
    if (k < npts) {
        float md = __uint_as_float(rev_min[k]);
        float p = fp[k / S];
        rsum = p * md;
        rmax = md;
    }
    if (k < fs) {
        float p = fp[k];
        fsum = p * __uint_as_float(fwd_min[k]) + PROB_PENALTYF * (1.0f - p);
    }
    s1[threadIdx.x] = fsum;
    s2[threadIdx.x] = rsum;
    s3[threadIdx.x] = rmax;
    __syncthreads();
    for (int off = FBLK / 2; off > 0; off >>= 1) {
        if ((int)threadIdx.x < off) {
            s1[threadIdx.x] += s1[threadIdx.x + off];
            s2[threadIdx.x] += s2[threadIdx.x + off];
            s3[threadIdx.x] = fmaxf(s3[threadIdx.x], s3[threadIdx.x + off]);
        }
        __syncthreads();
    }
    if (threadIdx.x == 0) {
        atomicAdd(&acc[0], s1[0]);
        atomicAdd(&acc[1], s2[0]);
        atomicMax((unsigned int*)&acc[2], __float_as_uint(s3[0]));
        __threadfence();
        unsigned int ticket = atomicAdd((unsigned int*)&acc[3], 1u);
        if (ticket == (unsigned int)(nblocks - 1)) {
            __threadfence();
            float a0 = atomicAdd(&acc[0], 0.0f);
            float a1 = atomicAdd(&acc[1], 0.0f);
            unsigned int mb = atomicOr((unsigned int*)&acc[2], 0u);
            out[0] = a0 + a1 * (REV_SCALEF / (__uint_as_float(mb) + EPSF));
        }
    }
}

extern "C" void kernel_launch(void* const* d_in, const int* in_sizes, int n_in,
                              void* d_out, int out_size, void* d_ws, size_t ws_size,
                              hipStream_t stream) {
    const float* overts = (const float*)d_in[0];
    const int*   ofaces = (const int*)d_in[1];
    const float* sverts = (const float*)d_in[2];
    const int*   sfaces = (const int*)d_in[3];
    const float* fp     = (const float*)d_in[4];
    const float* u1     = (const float*)d_in[5];
    const float* u2     = (const float*)d_in[6];
    float* out = (float*)d_out;

    const int N_ORIG = in_sizes[0] / 3;
    const int F_ORIG = in_sizes[1] / 3;
    const int F_SIMP = in_sizes[3] / 3;
    const int S      = in_sizes[5] / F_SIMP;
    const int NPTS   = F_SIMP * S;

    // tile counts (16 points/sources per tile)
    const int revPt = (NPTS + 15) / 16;      // 2000
    const int fwdPt = (F_SIMP + 15) / 16;    // 250
    const int revSt = (N_ORIG + 15) / 16;    // 500
    const int fwdSt = (F_ORIG + 15) / 16;    // 1000

    // workspace: revA | fwdA | revB | fwdB | rev_min | fwd_min | acc
    uint4* revA = (uint4*)d_ws;
    uint4* fwdA = revA + (size_t)revPt * 32;
    uint4* revB = fwdA + (size_t)fwdPt * 32;
    uint4* fwdB = revB + (size_t)revSt * 32;
    unsigned* rev_min = (unsigned*)(fwdB + (size_t)fwdSt * 32);
    unsigned* fwd_min = rev_min + NPTS;
    float* acc = (float*)(fwd_min + F_SIMP);

    // ---- prep ----
    int prepThreads = (revPt + fwdPt + revSt + fwdSt) * 32 + NPTS;
    hipLaunchKernelGGL(prep_kernel, dim3((prepThreads + 255) / 256), dim3(256), 0, stream,
                       overts, ofaces, sverts, sfaces, u1, u2,
                       revA, fwdA, revB, fwdB, rev_min, fwd_min, acc,
                       N_ORIG, F_ORIG, F_SIMP, S, NPTS,
                       revPt, fwdPt, revSt, fwdSt);

    // ---- mfma min ----
    // rev: 500 groups x 16 chunks (32 tiles) = 8000 waves
    // fwd: 63 groups x 32 chunks (32 tiles) = 2016 waves -> 10016 waves
    const int revGroups = (revPt + PTW - 1) / PTW;
    const int revChunks = (revSt + CS - 1) / CS;
    const int revWaves = revGroups * revChunks;

    const int fwdGroups = (fwdPt + PTW - 1) / PTW;
    const int fwdChunks = (fwdSt + CS - 1) / CS;
    const int fwdWaves = fwdGroups * fwdChunks;

    const int totalWaves = revWaves + fwdWaves;
    const int mblocks = (totalWaves + WPB - 1) / WPB;
    hipLaunchKernelGGL(mfma_min_kernel, dim3(mblocks), dim3(256), 0, stream,
                       revA, fwdA, revB, fwdB, rev_min, fwd_min,
                       revGroups, revWaves, revPt, NPTS, revSt,
                       fwdGroups, fwdPt, F_SIMP, fwdSt,
                       totalWaves);

    // ---- finalize ----
    const int finBlocks = (NPTS + FBLK - 1) / FBLK;
    hipLaunchKernelGGL(finalize_kernel, dim3(finBlocks), dim3(FBLK), 0, stream,
                       fwd_min, rev_min, fp, acc, out, F_SIMP, NPTS, S, finBlocks);
}